// Round 1
// baseline (250.301 us; speedup 1.0000x reference)
//
#include <hip/hip_runtime.h>
#include <stdint.h>

// ---------------------------------------------------------------------------
// Self-attention, B=4 S=2048 D=1024, fp32 in/out, fp16 MFMA compute.
//   0) cvt: x -> xh fp16; w_q/w_k/w_v -> wh fp16 (one dispatch)
//   1) proj z=3: z<2 -> q,k fp16 row-major; z==2 -> vt[b][d][s] (LDS transp.)
//   2) scores = q_b @ k_b^T -> fp16 (z=batch)
//   3) softmax rows in place fp16->fp16
//   4) out_b = attn_b @ vt_b^T (fp32)
// R7: K-loop rebuilt as a double-buffered counted-vmcnt pipeline (T3+T4+T5
// re-derived for the 256x128 tile): 2 phases per K-tile, one prefetch unit
// per phase (P1 issues B(t+1); P2 issues A(t+2) into the current buffer's
// dead A region), s_waitcnt vmcnt(4) ONCE per K-tile (never 0 in steady
// state), raw s_barrier (no vmcnt drain), s_setprio(1) around MFMA clusters.
// LDS 2 x (256+128)x64x2B = 96KB -> 1 block/CU (8 waves, 2/SIMD).
// Grids all balanced at 1 block/CU: proj 768 = 3 rounds, scores 512 = 2,
// out 256 = 1 (out BN 64 -> 128). XOR chunk swizzle + bm-fastest unchanged.
// Invariant: after vmcnt(4) at end of tile t, only A(t+2) is outstanding;
// tiles <= t+1 are fully landed before any wave reads them.
// ---------------------------------------------------------------------------

typedef __attribute__((ext_vector_type(8))) _Float16 f16x8;
typedef __attribute__((ext_vector_type(4))) float f32x4;
typedef __attribute__((ext_vector_type(4))) unsigned short u16x4;

__device__ inline unsigned short f2h(float f) {
    union { _Float16 h; unsigned short u; } x;
    x.h = (_Float16)f;   // RNE
    return x.u;
}
__device__ inline float h2f(unsigned short u) {
    union { unsigned short u; _Float16 h; } x;
    x.u = u;
    return (float)x.h;
}

__device__ inline void async16(const unsigned short* g, unsigned short* l) {
    __builtin_amdgcn_global_load_lds(
        (__attribute__((address_space(1))) void*)g,
        (__attribute__((address_space(3))) void*)l, 16, 0, 0);
}

// MODE 0: proj: z<2 -> fp16 row-major into C (+z*sCz);
//         z==2 -> vt transpose into C2 (vt[b][d][s], ld 2048, bstride 2^21).
// MODE 1: fp16 row-major into C (scores).
// MODE 2: fp32 row-major into C (final out).
// Tile: BM=256 x BN=128, BK=64. 8 waves: wr=wave>>1 (4 x 64 rows),
// wc=wave&1 (2 x 64 cols). Requires K >= 128 (ntiles >= 2).
template <int MODE, int BN>
__global__ __launch_bounds__(512)
void gemm512(const unsigned short* __restrict__ A,
             const unsigned short* __restrict__ B,
             void* __restrict__ C, void* __restrict__ C2,
             int K, int ldA, int ldB, int ldC,
             long sAz, long sBz, long sCz)
{
    static_assert(BN == 128, "pipeline is derived for BN=128");
    constexpr int NT = BN / 32;                 // 4 frag cols per wave
    constexpr int BI = BN / 64;                 // 2 B-stage chunks per thread
    constexpr int TILE = 256 * 64 + BN * 64;    // halves per K-tile buffer
    __shared__ __align__(16) unsigned short smem[2 * TILE];   // 96 KB

    const int tid  = threadIdx.x;
    const int lane = tid & 63;
    const int wave = tid >> 6;
    const int wr   = wave >> 1, wc = wave & 1;
    const int quad = lane >> 4, lrow = lane & 15;
    const int bm   = blockIdx.x, bn = blockIdx.y, z = blockIdx.z;  // bm fastest

    const unsigned short* Az = A + (long)z * sAz;
    const unsigned short* Bz = B + (long)z * sBz;

    // staging: 16B chunks; chunk l -> row l>>3, phys slot l&7, holding logical
    // k-chunk (l&7)^(row&7) (XOR swizzle). Thread t stages l = t + 512*i.
    const unsigned short* gA[4];
    const unsigned short* gB[BI];
#pragma unroll
    for (int i = 0; i < 4; ++i) {
        const int l = tid + 512 * i;
        const int r = l >> 3;
        const int c = (l & 7) ^ (r & 7);
        gA[i] = Az + (long)(bm * 256 + r) * ldA + c * 8;
    }
#pragma unroll
    for (int i = 0; i < BI; ++i) {
        const int l = tid + 512 * i;
        const int r = l >> 3;
        const int c = (l & 7) ^ (r & 7);
        gB[i] = Bz + (long)(bn * BN + r) * ldB + c * 8;
    }

    f32x4 acc[4][NT];
#pragma unroll
    for (int i = 0; i < 4; ++i)
#pragma unroll
        for (int j = 0; j < NT; ++j)
            acc[i][j] = f32x4{0.f, 0.f, 0.f, 0.f};

    const int fr = lrow & 7;   // row bits for fragment de-swizzle
    const int ntiles = K >> 6;

    // ---- prologue: tile0 {A0,A1,B} -> buf0 ; tile1 {A0,A1} -> buf1 ----
    // Issue order (oldest first) makes vmcnt(4) == "tile0 fully landed".
#pragma unroll
    for (int i = 0; i < 4; ++i)
        async16(gA[i], &smem[(tid + 512 * i) * 8]);
#pragma unroll
    for (int i = 0; i < BI; ++i)
        async16(gB[i], &smem[256 * 64 + (tid + 512 * i) * 8]);
#pragma unroll
    for (int i = 0; i < 4; ++i) {
        async16(gA[i] + 64, &smem[TILE + (tid + 512 * i) * 8]);
        gA[i] += 128;
    }
#pragma unroll
    for (int i = 0; i < BI; ++i) gB[i] += 64;

    asm volatile("s_waitcnt vmcnt(4)" ::: "memory");
    __builtin_amdgcn_s_barrier();

    for (int t = 0; t < ntiles; ++t) {
        const unsigned short* cA = smem + (t & 1) * TILE;
        const unsigned short* cB = cA + 256 * 64;
        unsigned short* nxt  = smem + ((t + 1) & 1) * TILE;  // tile t+1 buffer
        unsigned short* cur  = smem + (t & 1) * TILE;        // tile t+2 A dest

        // ---------- phase 1: all A frags + B cols 0,1 ----------
        f16x8 af[4][2], b0f[2][2];
#pragma unroll
        for (int ks = 0; ks < 2; ++ks) {
            const int pc = (((ks << 2) + quad) ^ fr) * 8;
#pragma unroll
            for (int mt = 0; mt < 4; ++mt)
                af[mt][ks] = *(const f16x8*)&cA[(wr * 64 + mt * 16 + lrow) * 64 + pc];
#pragma unroll
            for (int n = 0; n < 2; ++n)
                b0f[n][ks] = *(const f16x8*)&cB[(wc * (BN / 2) + n * 16 + lrow) * 64 + pc];
        }
        if (t + 1 < ntiles) {      // issue B(t+1); its region of nxt is dead
#pragma unroll
            for (int i = 0; i < BI; ++i) {
                async16(gB[i], &nxt[256 * 64 + (tid + 512 * i) * 8]);
                gB[i] += 64;
            }
        }
        __builtin_amdgcn_s_barrier();
        asm volatile("s_waitcnt lgkmcnt(0)");
        __builtin_amdgcn_s_setprio(1);
#pragma unroll
        for (int mt = 0; mt < 4; ++mt)
#pragma unroll
            for (int n = 0; n < 2; ++n)
#pragma unroll
                for (int ks = 0; ks < 2; ++ks)
                    acc[mt][n] = __builtin_amdgcn_mfma_f32_16x16x32_f16(
                        af[mt][ks], b0f[n][ks], acc[mt][n], 0, 0, 0);
        __builtin_amdgcn_s_setprio(0);
        __builtin_amdgcn_s_barrier();
        // all waves' A-reads of tile t done -> cur A region is now dead

        // ---------- phase 2: B cols 2,3 (af reused) ----------
        f16x8 b1f[2][2];
#pragma unroll
        for (int ks = 0; ks < 2; ++ks) {
            const int pc = (((ks << 2) + quad) ^ fr) * 8;
#pragma unroll
            for (int n = 0; n < 2; ++n)
                b1f[n][ks] = *(const f16x8*)&cB[(wc * (BN / 2) + (2 + n) * 16 + lrow) * 64 + pc];
        }
        if (t + 2 < ntiles) {      // issue A(t+2) into current buffer's A
#pragma unroll
            for (int i = 0; i < 4; ++i) {
                async16(gA[i], &cur[(tid + 512 * i) * 8]);
                gA[i] += 64;
            }
        }
        __builtin_amdgcn_s_barrier();
        asm volatile("s_waitcnt lgkmcnt(0)");
        __builtin_amdgcn_s_setprio(1);
#pragma unroll
        for (int mt = 0; mt < 4; ++mt)
#pragma unroll
            for (int n = 0; n < 2; ++n)
#pragma unroll
                for (int ks = 0; ks < 2; ++ks)
                    acc[mt][2 + n] = __builtin_amdgcn_mfma_f32_16x16x32_f16(
                        af[mt][ks], b1f[n][ks], acc[mt][2 + n], 0, 0, 0);
        __builtin_amdgcn_s_setprio(0);
        // counted wait: leaves only A(t+2) outstanding; tile t+1 fully landed
        if (t + 2 < ntiles)
            asm volatile("s_waitcnt vmcnt(4)" ::: "memory");
        else if (t + 1 < ntiles)
            asm volatile("s_waitcnt vmcnt(0)" ::: "memory");
        __builtin_amdgcn_s_barrier();
    }

    const int col_base = bn * BN + wc * (BN / 2);

    if (MODE != 0 || z < 2) {
        const int row_base = bm * 256 + wr * 64;
        const long zC = (long)z * sCz;
#pragma unroll
        for (int mt = 0; mt < 4; ++mt)
#pragma unroll
            for (int nt = 0; nt < NT; ++nt)
#pragma unroll
                for (int r = 0; r < 4; ++r) {
                    const int row = row_base + mt * 16 + quad * 4 + r;
                    const int col = col_base + nt * 16 + lrow;
                    if (MODE == 2)
                        ((float*)C)[zC + (long)row * ldC + col] = acc[mt][nt][r];
                    else
                        ((unsigned short*)C)[zC + (long)row * ldC + col] =
                            f2h(acc[mt][nt][r]);
                }
    } else {
        // vt transpose (BN=128): 4 phases of 64 token-rows. T[col 128][row 64]
        // pitch 72 halves (144B rows keep 16B align); aliases smem (dead).
        unsigned short* T = smem;   // 128*72 = 9216 halves
#pragma unroll
        for (int p = 0; p < 4; ++p) {
            __syncthreads();
            if (wr == p) {
#pragma unroll
                for (int mt = 0; mt < 4; ++mt)
#pragma unroll
                    for (int nt = 0; nt < NT; ++nt) {
                        const int row_l = mt * 16 + quad * 4;     // within band
                        const int col_l = wc * 64 + nt * 16 + lrow;
                        u16x4 pk = {f2h(acc[mt][nt][0]), f2h(acc[mt][nt][1]),
                                    f2h(acc[mt][nt][2]), f2h(acc[mt][nt][3])};
                        *(u16x4*)&T[col_l * 72 + row_l] = pk;
                    }
            }
            __syncthreads();
            // copy out: 128 cols x 64 rows = 8192 halves = 512 thr x 16
            const int c  = tid >> 2;
            const int j0 = (tid & 3) * 16;
            const int tok0 = bm * 256 + p * 64;   // 256-row tile never crosses
            const int bb = tok0 >> 11;            // a batch boundary (2048%256=0)
            const int s0 = (tok0 & 2047) + j0;
            unsigned short* dst = (unsigned short*)C2 + (long)bb * 2097152 +
                                  (long)(bn * 128 + c) * 2048 + s0;
            const unsigned short* srcT = &T[c * 72 + j0];
            *(f16x8*)dst = *(const f16x8*)srcT;
            *(f16x8*)(dst + 8) = *(const f16x8*)(srcT + 8);
        }
    }
}

// fused fp32 -> fp16 conversion: blocks [0,4096) -> x, [4096,5632) -> weights
__global__ __launch_bounds__(256)
void cvt_all(const float* __restrict__ x, const float* __restrict__ w0,
             const float* __restrict__ w1, const float* __restrict__ w2,
             unsigned short* __restrict__ xh, unsigned short* __restrict__ wh)
{
    const int bid = blockIdx.x;
    const float* s;
    unsigned short* d;
    long i;
    if (bid < 4096) {
        s = x; d = xh;
        i = ((long)bid * 256 + threadIdx.x) * 8;
    } else {
        const int wid = bid - 4096;          // [0,1536)
        const int w = wid >> 9;              // weight index
        s = (w == 0) ? w0 : (w == 1) ? w1 : w2;
        d = wh + (long)w * 1048576;
        i = ((long)(wid & 511) * 256 + threadIdx.x) * 8;
    }
    f32x4 a = *(const f32x4*)(s + i);
    f32x4 b = *(const f32x4*)(s + i + 4);
    union { unsigned short u[8]; f16x8 v; } t;
#pragma unroll
    for (int j = 0; j < 4; ++j) { t.u[j] = f2h(a[j]); t.u[4 + j] = f2h(b[j]); }
    *(f16x8*)(d + i) = t.v;
}

// in-place fp16 row softmax: row = 2048 fp16, one block per row.
__global__ __launch_bounds__(256)
void softmax16(unsigned short* __restrict__ sc)
{
    const long row = blockIdx.x;
    unsigned short* srow = sc + row * 2048;
    const int tid = threadIdx.x;

    union { u16x4 p[2]; unsigned short u[8]; } in;
    in.p[0] = *(const u16x4*)(srow + tid * 8);
    in.p[1] = *(const u16x4*)(srow + tid * 8 + 4);
    float v[8];
#pragma unroll
    for (int i = 0; i < 8; ++i) v[i] = h2f(in.u[i]);

    float m = v[0];
#pragma unroll
    for (int i = 1; i < 8; ++i) m = fmaxf(m, v[i]);
#pragma unroll
    for (int off = 32; off; off >>= 1) m = fmaxf(m, __shfl_xor(m, off));

    __shared__ float redm[4], reds[4];
    if ((tid & 63) == 0) redm[tid >> 6] = m;
    __syncthreads();
    m = fmaxf(fmaxf(redm[0], redm[1]), fmaxf(redm[2], redm[3]));

    float s = 0.f;
#pragma unroll
    for (int i = 0; i < 8; ++i) { v[i] = __expf(v[i] - m); s += v[i]; }
#pragma unroll
    for (int off = 32; off; off >>= 1) s += __shfl_xor(s, off);
    if ((tid & 63) == 0) reds[tid >> 6] = s;
    __syncthreads();
    s = reds[0] + reds[1] + reds[2] + reds[3];

    const float inv = 1.f / s;
    union { unsigned short u[8]; f16x8 w; } t;
#pragma unroll
    for (int i = 0; i < 8; ++i) t.u[i] = f2h(v[i] * inv);
    *(f16x8*)(srow + tid * 8) = t.w;
}

extern "C" void kernel_launch(void* const* d_in, const int* in_sizes, int n_in,
                              void* d_out, int out_size, void* d_ws, size_t ws_size,
                              hipStream_t stream)
{
    const float* x  = (const float*)d_in[0];
    const float* wq = (const float*)d_in[1];
    const float* wk = (const float*)d_in[2];
    const float* wv = (const float*)d_in[3];
    float* out = (float*)d_out;

    // batched: [sc fp16 33.5MB (aliases xh 16.8 | wh 6.3)] [q][k][vt] = 83.9MB
    // looped:  [xh|wh 23.1MB (per-batch sc fp16 8.4MB aliases xh)][q][k][vt]
    //          = 73.4MB
    char* base = (char*)d_ws;
    const bool batched = (ws_size >= 88080384UL);   // 84 MB

    unsigned short* xh = (unsigned short*)base;
    unsigned short* wh = (unsigned short*)(base + 16777216);
    unsigned short* sc = (unsigned short*)base;
    unsigned short* q  = (unsigned short*)(base + (batched ? 33554432 : 23068672));
    unsigned short* k  = q + 8388608;
    unsigned short* vt = k + 8388608;

    // 0) conversions (single dispatch)
    cvt_all<<<5632, 256, 0, stream>>>(x, wq, wk, wv, xh, wh);

    // 1) fused projections: M=8192 N=1024 K=1024; z=0,1 -> q,k; z=2 -> vt
    //    grid (32,8,3) = 768 blocks = 3 balanced rounds at 1 block/CU
    gemm512<0, 128><<<dim3(32, 8, 3), 512, 0, stream>>>(
        xh, wh, q, vt, 1024, 1024, 1024, 1024, 0L, 1048576L, 8388608L);

    if (batched) {
        // 2) scores fp16: M=N=2048 K=1024, z=batch; (8,16,4)=512 = 2 rounds
        gemm512<1, 128><<<dim3(8, 16, 4), 512, 0, stream>>>(
            q, k, sc, nullptr, 1024, 1024, 1024, 2048,
            2097152L, 2097152L, 4194304L);
        // 3) softmax in place (8192 rows, fp16->fp16)
        softmax16<<<8192, 256, 0, stream>>>(sc);
        // 4) out: M=2048 N=1024 K=2048; 256x128 tiles, (8,8,4)=256 = 1 round
        gemm512<2, 128><<<dim3(8, 8, 4), 512, 0, stream>>>(
            sc, vt, out, nullptr, 2048, 2048, 2048, 1024,
            4194304L, 2097152L, 2097152L);
    } else {
        for (int b = 0; b < 4; ++b) {
            gemm512<1, 128><<<dim3(8, 16, 1), 512, 0, stream>>>(
                q + (long)b * 2097152, k + (long)b * 2097152, sc, nullptr,
                1024, 1024, 1024, 2048, 0L, 0L, 0L);
            softmax16<<<2048, 256, 0, stream>>>(sc);
            gemm512<2, 128><<<dim3(8, 8, 1), 512, 0, stream>>>(
                sc, vt + (long)b * 2097152, out + (long)b * 2097152, nullptr,
                2048, 2048, 2048, 1024, 0L, 0L, 0L);
        }
    }
}